// Round 1
// 456.392 us; speedup vs baseline: 1.0652x; 1.0652x over previous
//
#include <hip/hip_runtime.h>
#include <stdint.h>

// TankModel v2: B=8192 chains, T=4096 serial steps, 4 lanes/chain systolic.
// Wall = per-wave II (512 waves on 1024 SIMDs; occupancy irrelevant).
// r4 (this): strip the recurrence to minimum II.
//  - quad_perm[3,0,1,2] rotate: lane k <- k-1 in its 4-lane quad, lane0 <-
//    lane3. Lane3 carries the NEXT p in the rotating 'hand' reg, so lane0's
//    rain arrives through the same rotate: no is0 cndmask, no p-add.
//  - w' = (t - riN*relu(t)) - (a1+a2): 5-deep loop-carried chain (was 7).
//  - warm-up freeze cndmask only in peeled tile 0.
//  - len-mask + Area/3.6 scale moved to the per-tile coop-store.
//  - p broadcast ds_read prefetch depth 3.
// Staging/out machinery identical to the verified r3 kernel.

__device__ __forceinline__ float quad_rot1(float x) {
    int xi = __builtin_bit_cast(int, x);
    // quad_perm: dest lane {0,1,2,3} <- src lane {3,0,1,2} of the same quad
    int r = __builtin_amdgcn_update_dpp(xi, xi, 0x93, 0xF, 0xF, false);
    return __builtin_bit_cast(float, r);
}

__global__ __launch_bounds__(64)
void tank_kernel(
    const float* __restrict__ P,
    const int*   __restrict__ lengths,
    const float* __restrict__ S0,
    const float* __restrict__ AreaP,
    const float* __restrict__ p_r1h1, const float* __restrict__ p_r1h2,
    const float* __restrict__ p_h1h1, const float* __restrict__ p_h1h2,
    const float* __restrict__ p_ri2,  const float* __restrict__ p_ro2,
    const float* __restrict__ p_h2,
    const float* __restrict__ p_ri3,  const float* __restrict__ p_ro3,
    const float* __restrict__ p_h3,
    const float* __restrict__ p_ri4,  const float* __restrict__ p_ro4,
    float* __restrict__ Out,
    int B, int T)
{
    __shared__ float4 inbuf[2 * 256];   // 2 x [16 rows][16 float4], XOR swizzle
    __shared__ float4 outbuf[3 * 256];  // 3 x [16 rows][16 float4]

    const int tid = threadIdx.x;
    const int g   = tid >> 2;          // group = chain row within block
    const int k   = tid & 3;           // tank role 0..3
    const int row = blockIdx.x * 16 + g;
    const int rowc = (row < B) ? row : (B - 1);
    const bool is3 = (k == 3);
    const float zk = (k == 0) ? 0.0f : 1.0f;   // kills lane3->lane0 psum wrap

    const float v_r1h1 = p_r1h1[0], v_r1h2 = p_r1h2[0];
    const float v_h11 = p_h1h1[0], v_h12 = p_h1h2[0];
    const float v_ri2 = p_ri2[0], v_ro2 = p_ro2[0], v_h2 = p_h2[0];
    const float v_ri3 = p_ri3[0], v_ro3 = p_ro3[0], v_h3 = p_h3[0];
    const float v_ri4 = p_ri4[0], v_ro4 = p_ro4[0];
    const float scale = AreaP[0] * (1.0f / 3.6f);

    // Per-lane tank constants.
    float rA = v_ro4, kA = 0.0f, rB = 0.0f, kB = 0.0f, riN = 0.0f;
    if (k == 0) { rA = v_r1h1; kA = -v_r1h1 * v_h11; rB = v_r1h2; kB = -v_r1h2 * v_h12; riN = v_ri2; }
    else if (k == 1) { rA = v_ro2; kA = -v_ro2 * v_h2; riN = v_ri3; }
    else if (k == 2) { rA = v_ro3; kA = -v_ro3 * v_h3; riN = v_ri4; }

    float w = (k == 0) ? S0[0] : (k == 1) ? S0[1] : (k == 2) ? S0[2] : S0[3];

    int len = lengths[rowc];
    if (len > T) len = T;
    if (len < 0) len = 0;

    float psum = 0.0f;          // running outflow sum, hops lane j-1 -> j
    float hand = 0.0f;          // flow (lanes 0-2) / next-p (lane 3) carrier
    float4 o = make_float4(0.0f, 0.0f, 0.0f, 0.0f);
    const int ntiles = T / 64;

// Lean steady-state step. Loop-carried chains:
//   w:    w -> t -> a1f -> a1 -> Y -> w            (5)
//   hand: hand -> rot -> t -> e3 -> fl -> cndmask  (5)
#define STEP(HANDC, ii, ocomp) do {                          \
        float in_   = quad_rot1(hand);                       \
        float prin_ = quad_rot1(psum);                       \
        float t_  = w + in_;                                 \
        float a1_ = fmaxf(fmaf(rA, t_, kA), 0.0f);           \
        float a2_ = fmaxf(fmaf(rB, t_, kB), 0.0f);           \
        float e3_ = fmaxf(t_, 0.0f);                         \
        float fl_ = riN * e3_;                               \
        float Y_  = a1_ + a2_;                               \
        w = (t_ - fl_) - Y_;                                 \
        psum = fmaf(prin_, zk, Y_);                          \
        hand = is3 ? (HANDC) : fl_;                          \
        (ocomp) = psum;                                      \
    } while (0)

// Warm-up variant (tile 0 only): freeze w until lane's first real step.
#define STEPW(HANDC, ii, ocomp) do {                         \
        float in_   = quad_rot1(hand);                       \
        float prin_ = quad_rot1(psum);                       \
        float t_  = w + in_;                                 \
        float a1_ = fmaxf(fmaf(rA, t_, kA), 0.0f);           \
        float a2_ = fmaxf(fmaf(rB, t_, kB), 0.0f);           \
        float e3_ = fmaxf(t_, 0.0f);                         \
        float fl_ = riN * e3_;                               \
        float Y_  = a1_ + a2_;                               \
        float wn_ = (t_ - fl_) - Y_;                         \
        w = ((ii) >= k) ? wn_ : w;                           \
        psum = fmaf(prin_, zk, Y_);                          \
        hand = is3 ? (HANDC) : fl_;                          \
        (ocomp) = psum;                                      \
    } while (0)

#define STAGE_LOAD(mt) do {                                               \
        const float* src_ = P + (size_t)rowc * T + (mt) * 64;             \
        _Pragma("unroll")                                                 \
        for (int r = 0; r < 4; ++r)                                       \
            st[r] = *reinterpret_cast<const float4*>(src_ + (4 * r + k) * 4); \
    } while (0)

#define STAGE_LDS(ibp) do {                                  \
        _Pragma("unroll")                                    \
        for (int r = 0; r < 4; ++r)                          \
            (ibp)[g * 16 + ((4 * r + k) ^ g)] = st[r];       \
    } while (0)

// Coop-store out-tile mt with scale + length masking (moved out of step loop).
#define OUT_STORE(mt) do {                                                \
        const float4* ob_ = outbuf + ((mt) % 3) * 256;                    \
        const int col0_ = (mt) * 64;                                      \
        _Pragma("unroll")                                                 \
        for (int r = 0; r < 4; ++r) {                                     \
            float4 v_ = ob_[g * 16 + ((4 * r + k) ^ g)];                  \
            const int cb_ = col0_ + (4 * r + k) * 4;                      \
            float4 s_;                                                    \
            s_.x = (cb_ + 0 < len) ? v_.x * scale : 0.0f;                 \
            s_.y = (cb_ + 1 < len) ? v_.y * scale : 0.0f;                 \
            s_.z = (cb_ + 2 < len) ? v_.z * scale : 0.0f;                 \
            s_.w = (cb_ + 3 < len) ? v_.w * scale : 0.0f;                 \
            if (row < B)                                                  \
                *reinterpret_cast<float4*>(Out + (size_t)row * T + cb_) = s_; \
        }                                                                 \
    } while (0)

// 64 systolic iterations over one staged tile. Broadcast p read (4 lanes of a
// group share one address), prefetch depth 3. Lane3 re-arms 'hand' with the
// tile's first p (cross-tile p handoff).
#define TILE_BODY(STEPM, GUARD0, i0v, ibp) do {                           \
        float4 c0 = (ibp)[g * 16 + (0 ^ g)];                              \
        float4 c1 = (ibp)[g * 16 + (1 ^ g)];                              \
        float4 c2 = (ibp)[g * 16 + (2 ^ g)];                              \
        hand = is3 ? c0.x : hand;                                         \
        _Pragma("unroll 4")                                               \
        for (int j4 = 0; j4 < 16; ++j4) {                                 \
            float4 c3 = (ibp)[g * 16 + ((((j4 + 3) & 15)) ^ g)];          \
            const int i_ = (i0v) + 4 * j4;                                \
            STEPM(c0.y, i_ + 0, o.y);                                     \
            STEPM(c0.z, i_ + 1, o.z);                                     \
            STEPM(c0.w, i_ + 2, o.w);                                     \
            const int b_ = ((i0v) >> 2) + j4 - 1;                         \
            if ((!(GUARD0) || b_ >= 0) && is3) {                          \
                float4* obp_ = outbuf + ((b_ >> 4) % 3) * 256;            \
                obp_[g * 16 + ((b_ & 15) ^ g)] = o;                       \
            }                                                             \
            STEPM(c1.x, i_ + 3, o.x);                                     \
            c0 = c1; c1 = c2; c2 = c3;                                    \
        }                                                                 \
    } while (0)

    // ---- tile 0 (peeled: warm-up freeze active) ----
    float4 st[4];
    STAGE_LOAD(0);
    STAGE_LDS(inbuf);
    __syncthreads();
    if (ntiles > 1) STAGE_LOAD(1);
    TILE_BODY(STEPW, 1, 0, inbuf);

    // ---- main tiles: lean step ----
    for (int m = 1; m < ntiles; ++m) {
        float4* ib = inbuf + (m & 1) * 256;
        STAGE_LDS(ib);
        __syncthreads();
        if (m >= 2) OUT_STORE(m - 2);
        if (m + 1 < ntiles) STAGE_LOAD(m + 1);
        TILE_BODY(STEP, 0, m * 64, ib);
    }

    // Drain: 3 iters so lane3 reaches t = T-1 (p dead: t >= len always).
    STEP(0.0f, 0, o.y);
    STEP(0.0f, 0, o.z);
    STEP(0.0f, 0, o.w);
    {
        const int lastb = (T >> 2) - 1;
        if (is3) {
            float4* obp = outbuf + ((lastb >> 4) % 3) * 256;
            obp[g * 16 + ((lastb & 15) ^ g)] = o;
        }
    }
#undef STEP
#undef STEPW
#undef TILE_BODY

    // Epilogue: store out-tiles ntiles-2, ntiles-1.
    __syncthreads();
    OUT_STORE(ntiles - 2);
    OUT_STORE(ntiles - 1);
#undef OUT_STORE
#undef STAGE_LOAD
#undef STAGE_LDS
}

extern "C" void kernel_launch(void* const* d_in, const int* in_sizes, int n_in,
                              void* d_out, int out_size, void* d_ws, size_t ws_size,
                              hipStream_t stream) {
    const float* P        = (const float*)d_in[0];
    const int*   lengths  = (const int*)d_in[1];
    const float* S0       = (const float*)d_in[2];
    const float* Area     = (const float*)d_in[3];
    // d_in[4] = baseflow (unused by forward)
    const float* r1h1 = (const float*)d_in[5];
    const float* r1h2 = (const float*)d_in[6];
    const float* h1h1 = (const float*)d_in[7];
    const float* h1h2 = (const float*)d_in[8];
    const float* ri2  = (const float*)d_in[9];
    const float* ro2  = (const float*)d_in[10];
    const float* h2   = (const float*)d_in[11];
    const float* ri3  = (const float*)d_in[12];
    const float* ro3  = (const float*)d_in[13];
    const float* h3   = (const float*)d_in[14];
    const float* ri4  = (const float*)d_in[15];
    const float* ro4  = (const float*)d_in[16];
    float* out = (float*)d_out;

    const int B = in_sizes[1];
    const int T = in_sizes[0] / B;

    dim3 block(64);
    dim3 grid((B + 15) / 16);   // 16 chains per block (4 lanes/chain)
    hipLaunchKernelGGL(tank_kernel, grid, block, 0, stream,
                       P, lengths, S0, Area,
                       r1h1, r1h2, h1h1, h1h2,
                       ri2, ro2, h2, ri3, ro3, h3, ri4, ro4,
                       out, B, T);
}

// Round 3
// 439.712 us; speedup vs baseline: 1.1056x; 1.0379x over previous
//
#include <hip/hip_runtime.h>
#include <stdint.h>

// TankModel v3.1: B=8192 chains, T=4096 serial steps, 4 lanes/chain systolic.
// Wall = per-chain elapsed = T x per-step critical path (512 waves over 1024
// SIMDs; occupancy is not a lever).
// r5 (block-systolic, 4 timesteps/hop) FAILED: DPP inside a ternary ->
// clang lowers the builtin call as a BRANCH -> DPP runs with lane0 masked
// off -> with bound_ctrl=false, lane1 reads its OWN old value instead of
// lane0's flow. r6 (this): hoist all DPPs to unconditional statements;
// select afterwards on plain floats (same pattern the passing r4 used).
//  - lane k processes tank k for a BLOCK of 4 timesteps; flows + psums hop
//    lane k->k+1 once per block (8 DPPs/hop, consumed >=3 steps later: off
//    the critical path).
//  - lane0's inflow = the broadcast p float4 directly; no per-step carrier.
//  - steady-state loop-carried chain = pure w recurrence:
//    w -> t -> fma -> max -> add -> sub -> w'  (5 deps, no cross-lane).
//  - lane3 completes one float4 of outputs per hop -> outbuf.
// Staging / out-store / len-mask machinery identical to verified r4.

__device__ __forceinline__ float quad_rot1(float x) {
    int xi = __builtin_bit_cast(int, x);
    // quad_perm: dest lane {0,1,2,3} <- src lane {3,0,1,2} of the same quad
    int r = __builtin_amdgcn_update_dpp(xi, xi, 0x93, 0xF, 0xF, false);
    return __builtin_bit_cast(float, r);
}

__global__ __launch_bounds__(64)
void tank_kernel(
    const float* __restrict__ P,
    const int*   __restrict__ lengths,
    const float* __restrict__ S0,
    const float* __restrict__ AreaP,
    const float* __restrict__ p_r1h1, const float* __restrict__ p_r1h2,
    const float* __restrict__ p_h1h1, const float* __restrict__ p_h1h2,
    const float* __restrict__ p_ri2,  const float* __restrict__ p_ro2,
    const float* __restrict__ p_h2,
    const float* __restrict__ p_ri3,  const float* __restrict__ p_ro3,
    const float* __restrict__ p_h3,
    const float* __restrict__ p_ri4,  const float* __restrict__ p_ro4,
    float* __restrict__ Out,
    int B, int T)
{
    __shared__ float4 inbuf[2 * 256];   // 2 x [16 rows][16 float4], XOR swizzle
    __shared__ float4 outbuf[3 * 256];  // 3 x [16 rows][16 float4]

    const int tid = threadIdx.x;
    const int g   = tid >> 2;          // group = chain row within block
    const int k   = tid & 3;           // tank role 0..3
    const int row = blockIdx.x * 16 + g;
    const int rowc = (row < B) ? row : (B - 1);
    const bool is0 = (k == 0);
    const bool is3 = (k == 3);
    const float zk = (k == 0) ? 0.0f : 1.0f;   // kills lane3->lane0 psum wrap

    const float v_r1h1 = p_r1h1[0], v_r1h2 = p_r1h2[0];
    const float v_h11 = p_h1h1[0], v_h12 = p_h1h2[0];
    const float v_ri2 = p_ri2[0], v_ro2 = p_ro2[0], v_h2 = p_h2[0];
    const float v_ri3 = p_ri3[0], v_ro3 = p_ro3[0], v_h3 = p_h3[0];
    const float v_ri4 = p_ri4[0], v_ro4 = p_ro4[0];
    const float scale = AreaP[0] * (1.0f / 3.6f);

    // Per-lane tank constants.
    float rA = v_ro4, kA = 0.0f, rB = 0.0f, kB = 0.0f, riN = 0.0f;
    if (k == 0) { rA = v_r1h1; kA = -v_r1h1 * v_h11; rB = v_r1h2; kB = -v_r1h2 * v_h12; riN = v_ri2; }
    else if (k == 1) { rA = v_ro2; kA = -v_ro2 * v_h2; riN = v_ri3; }
    else if (k == 2) { rA = v_ro3; kA = -v_ro3 * v_h3; riN = v_ri4; }

    float w = (k == 0) ? S0[0] : (k == 1) ? S0[1] : (k == 2) ? S0[2] : S0[3];

    int len = lengths[rowc];
    if (len > T) len = T;
    if (len < 0) len = 0;

    // Block-systolic state: this lane's 4 outflows / 4 running sums for the
    // block it just processed (rotated to the next lane at the next hop).
    float fl0 = 0.0f, fl1 = 0.0f, fl2 = 0.0f, fl3 = 0.0f;
    float ps0 = 0.0f, ps1 = 0.0f, ps2 = 0.0f, ps3 = 0.0f;
    const int ntiles = T / 64;

// One hop = 4 timesteps of one block. All 8 DPPs are UNCONDITIONAL
// statements (convergent: must not sit under a lane-divergent branch);
// the lane-0 select happens afterwards on plain floats. Rotated values are
// consumed >=3 steps after the rotate: off the critical path. FREEZE (tile 0
// only) holds w until this lane's first real hop (hidx >= k).
#define HOP4(CX, CY, CZ, CW, FREEZE, hidx) do {                   \
        float r0_ = quad_rot1(fl0);                               \
        float r1_ = quad_rot1(fl1);                               \
        float r2_ = quad_rot1(fl2);                               \
        float r3_ = quad_rot1(fl3);                               \
        float q0_ = quad_rot1(ps0);                               \
        float q1_ = quad_rot1(ps1);                               \
        float q2_ = quad_rot1(ps2);                               \
        float q3_ = quad_rot1(ps3);                               \
        float i0_ = is0 ? (CX) : r0_;                             \
        float i1_ = is0 ? (CY) : r1_;                             \
        float i2_ = is0 ? (CZ) : r2_;                             \
        float i3_ = is0 ? (CW) : r3_;                             \
        float t_, a1_, a2_, e_, Y_, wn_;                          \
        /* step 0 */                                              \
        t_  = w + i0_;                                            \
        a1_ = fmaxf(fmaf(rA, t_, kA), 0.0f);                      \
        a2_ = fmaxf(fmaf(rB, t_, kB), 0.0f);                      \
        e_  = fmaxf(t_, 0.0f);                                    \
        fl0 = riN * e_;                                           \
        Y_  = a1_ + a2_;                                          \
        wn_ = (t_ - fl0) - Y_;                                    \
        w = (FREEZE) ? (((hidx) >= k) ? wn_ : w) : wn_;           \
        ps0 = fmaf(q0_, zk, Y_);                                  \
        /* step 1 */                                              \
        t_  = w + i1_;                                            \
        a1_ = fmaxf(fmaf(rA, t_, kA), 0.0f);                      \
        a2_ = fmaxf(fmaf(rB, t_, kB), 0.0f);                      \
        e_  = fmaxf(t_, 0.0f);                                    \
        fl1 = riN * e_;                                           \
        Y_  = a1_ + a2_;                                          \
        wn_ = (t_ - fl1) - Y_;                                    \
        w = (FREEZE) ? (((hidx) >= k) ? wn_ : w) : wn_;           \
        ps1 = fmaf(q1_, zk, Y_);                                  \
        /* step 2 */                                              \
        t_  = w + i2_;                                            \
        a1_ = fmaxf(fmaf(rA, t_, kA), 0.0f);                      \
        a2_ = fmaxf(fmaf(rB, t_, kB), 0.0f);                      \
        e_  = fmaxf(t_, 0.0f);                                    \
        fl2 = riN * e_;                                           \
        Y_  = a1_ + a2_;                                          \
        wn_ = (t_ - fl2) - Y_;                                    \
        w = (FREEZE) ? (((hidx) >= k) ? wn_ : w) : wn_;           \
        ps2 = fmaf(q2_, zk, Y_);                                  \
        /* step 3 */                                              \
        t_  = w + i3_;                                            \
        a1_ = fmaxf(fmaf(rA, t_, kA), 0.0f);                      \
        a2_ = fmaxf(fmaf(rB, t_, kB), 0.0f);                      \
        e_  = fmaxf(t_, 0.0f);                                    \
        fl3 = riN * e_;                                           \
        Y_  = a1_ + a2_;                                          \
        wn_ = (t_ - fl3) - Y_;                                    \
        w = (FREEZE) ? (((hidx) >= k) ? wn_ : w) : wn_;           \
        ps3 = fmaf(q3_, zk, Y_);                                  \
    } while (0)

#define STAGE_LOAD(mt) do {                                               \
        const float* src_ = P + (size_t)rowc * T + (mt) * 64;             \
        _Pragma("unroll")                                                 \
        for (int r = 0; r < 4; ++r)                                       \
            st[r] = *reinterpret_cast<const float4*>(src_ + (4 * r + k) * 4); \
    } while (0)

#define STAGE_LDS(ibp) do {                                  \
        _Pragma("unroll")                                    \
        for (int r = 0; r < 4; ++r)                          \
            (ibp)[g * 16 + ((4 * r + k) ^ g)] = st[r];       \
    } while (0)

// Coop-store out-tile mt with scale + length masking.
#define OUT_STORE(mt) do {                                                \
        const float4* ob_ = outbuf + ((mt) % 3) * 256;                    \
        const int col0_ = (mt) * 64;                                      \
        _Pragma("unroll")                                                 \
        for (int r = 0; r < 4; ++r) {                                     \
            float4 v_ = ob_[g * 16 + ((4 * r + k) ^ g)];                  \
            const int cb_ = col0_ + (4 * r + k) * 4;                      \
            float4 s_;                                                    \
            s_.x = (cb_ + 0 < len) ? v_.x * scale : 0.0f;                 \
            s_.y = (cb_ + 1 < len) ? v_.y * scale : 0.0f;                 \
            s_.z = (cb_ + 2 < len) ? v_.z * scale : 0.0f;                 \
            s_.w = (cb_ + 3 < len) ? v_.w * scale : 0.0f;                 \
            if (row < B)                                                  \
                *reinterpret_cast<float4*>(Out + (size_t)row * T + cb_) = s_; \
        }                                                                 \
    } while (0)

// 16 hops over one staged tile. Lane0 consumes p block directly from the
// broadcast read (4 lanes/group share one addr). Lane3 completes one output
// block per hop -> outbuf (guarded for pipeline warm-up in tile 0).
#define TILE_BODY(FREEZE, h0, ibp) do {                                   \
        float4 c0 = (ibp)[g * 16 + (0 ^ g)];                              \
        float4 c1 = (ibp)[g * 16 + (1 ^ g)];                              \
        _Pragma("unroll 4")                                               \
        for (int j4 = 0; j4 < 16; ++j4) {                                 \
            float4 c2 = (ibp)[g * 16 + (((j4 + 2) & 15) ^ g)];            \
            HOP4(c0.x, c0.y, c0.z, c0.w, FREEZE, j4);                     \
            const int b_ = (h0) + j4 - 3;                                 \
            if ((!(FREEZE) || b_ >= 0) && is3) {                          \
                float4* obp_ = outbuf + ((b_ >> 4) % 3) * 256;            \
                obp_[g * 16 + ((b_ & 15) ^ g)] =                          \
                    make_float4(ps0, ps1, ps2, ps3);                      \
            }                                                             \
            c0 = c1; c1 = c2;                                             \
        }                                                                 \
    } while (0)

    // ---- tile 0 (peeled: warm-up freeze active) ----
    float4 st[4];
    STAGE_LOAD(0);
    STAGE_LDS(inbuf);
    __syncthreads();
    if (ntiles > 1) STAGE_LOAD(1);
    TILE_BODY(1, 0, inbuf);

    // ---- main tiles ----
    for (int m = 1; m < ntiles; ++m) {
        float4* ib = inbuf + (m & 1) * 256;
        STAGE_LDS(ib);
        __syncthreads();
        if (m >= 2) OUT_STORE(m - 2);
        if (m + 1 < ntiles) STAGE_LOAD(m + 1);
        TILE_BODY(0, m * 16, ib);
    }

    // Drain: 3 hops so lane3 completes blocks T/4-3 .. T/4-1. Lane0's p is
    // dead (its block indices >= T); rotated real data still propagates.
    {
        const int nb = T >> 2;
        #pragma unroll
        for (int d = 0; d < 3; ++d) {
            HOP4(0.0f, 0.0f, 0.0f, 0.0f, 0, 0);
            const int b_ = nb - 3 + d;
            if (is3) {
                float4* obp = outbuf + ((b_ >> 4) % 3) * 256;
                obp[g * 16 + ((b_ & 15) ^ g)] = make_float4(ps0, ps1, ps2, ps3);
            }
        }
    }
#undef HOP4
#undef TILE_BODY

    // Epilogue: store out-tiles ntiles-2, ntiles-1.
    __syncthreads();
    OUT_STORE(ntiles - 2);
    OUT_STORE(ntiles - 1);
#undef OUT_STORE
#undef STAGE_LOAD
#undef STAGE_LDS
}

extern "C" void kernel_launch(void* const* d_in, const int* in_sizes, int n_in,
                              void* d_out, int out_size, void* d_ws, size_t ws_size,
                              hipStream_t stream) {
    const float* P        = (const float*)d_in[0];
    const int*   lengths  = (const int*)d_in[1];
    const float* S0       = (const float*)d_in[2];
    const float* Area     = (const float*)d_in[3];
    // d_in[4] = baseflow (unused by forward)
    const float* r1h1 = (const float*)d_in[5];
    const float* r1h2 = (const float*)d_in[6];
    const float* h1h1 = (const float*)d_in[7];
    const float* h1h2 = (const float*)d_in[8];
    const float* ri2  = (const float*)d_in[9];
    const float* ro2  = (const float*)d_in[10];
    const float* h2   = (const float*)d_in[11];
    const float* ri3  = (const float*)d_in[12];
    const float* ro3  = (const float*)d_in[13];
    const float* h3   = (const float*)d_in[14];
    const float* ri4  = (const float*)d_in[15];
    const float* ro4  = (const float*)d_in[16];
    float* out = (float*)d_out;

    const int B = in_sizes[1];
    const int T = in_sizes[0] / B;

    dim3 block(64);
    dim3 grid((B + 15) / 16);   // 16 chains per block (4 lanes/chain)
    hipLaunchKernelGGL(tank_kernel, grid, block, 0, stream,
                       P, lengths, S0, Area,
                       r1h1, r1h2, h1h1, h1h2,
                       ri2, ro2, h2, ri3, ro3, h3, ri4, ro4,
                       out, B, T);
}

// Round 4
// 379.401 us; speedup vs baseline: 1.2813x; 1.1590x over previous
//
#include <hip/hip_runtime.h>
#include <stdint.h>

// TankModel v4: B=8192 chains, T=4096 serial steps, 4 lanes/chain,
// block-systolic (4 timesteps/hop). Wall = per-chain elapsed (512 waves on
// 1024 SIMDs; occupancy is not a lever).
// r6 post-mortem: moving DPPs off the critical path changed nothing
// (157 -> 152 cyc/step): the wall is NOT inst count / DPP chain. Suspects:
// exposed LDS-read latency (compiler sinks prefetched ds_reads at 88 VGPR;
// lone-wave SIMD eats ~120cyc/read) + per-tile barrier vmcnt/lgkm drains.
// r7 (this): NO LDS on the input path, NO barriers.
//  - p tile lives in regs (stA/stB double buffer, global->reg, 1-tile
//    prefetch distance). Hop j's p block = quad_perm BROADCAST from lane
//    j&3 of st[j>>2] (compile-time dpp ctrl under full unroll): 4 DPP/hop,
//    no memory op, off the critical path.
//  - outbuf (lane3 results -> coalesced len-masked stores) kept; block = 1
//    wave so same-wave in-order LDS needs no barrier.
//  - HOP4 / freeze / drain / OUT_STORE logic verbatim from passing r6.

__device__ __forceinline__ float quad_rot1(float x) {
    int xi = __builtin_bit_cast(int, x);
    // quad_perm: dest lane {0,1,2,3} <- src lane {3,0,1,2} of the same quad
    int r = __builtin_amdgcn_update_dpp(xi, xi, 0x93, 0xF, 0xF, false);
    return __builtin_bit_cast(float, r);
}

// Broadcast lane (s&3) of each quad to all 4 lanes. s must be a constant
// after unrolling (switch folds); DPPs sit in convergent straight-line code.
__device__ __forceinline__ float quad_bcast(float x, int s) {
    int xi = __builtin_bit_cast(int, x);
    int r;
    switch (s & 3) {
    case 0:  r = __builtin_amdgcn_update_dpp(xi, xi, 0x00, 0xF, 0xF, false); break;
    case 1:  r = __builtin_amdgcn_update_dpp(xi, xi, 0x55, 0xF, 0xF, false); break;
    case 2:  r = __builtin_amdgcn_update_dpp(xi, xi, 0xAA, 0xF, 0xF, false); break;
    default: r = __builtin_amdgcn_update_dpp(xi, xi, 0xFF, 0xF, 0xF, false); break;
    }
    return __builtin_bit_cast(float, r);
}

__global__ __launch_bounds__(64)
void tank_kernel(
    const float* __restrict__ P,
    const int*   __restrict__ lengths,
    const float* __restrict__ S0,
    const float* __restrict__ AreaP,
    const float* __restrict__ p_r1h1, const float* __restrict__ p_r1h2,
    const float* __restrict__ p_h1h1, const float* __restrict__ p_h1h2,
    const float* __restrict__ p_ri2,  const float* __restrict__ p_ro2,
    const float* __restrict__ p_h2,
    const float* __restrict__ p_ri3,  const float* __restrict__ p_ro3,
    const float* __restrict__ p_h3,
    const float* __restrict__ p_ri4,  const float* __restrict__ p_ro4,
    float* __restrict__ Out,
    int B, int T)
{
    __shared__ float4 outbuf[3 * 256];  // 3 x [16 rows][16 float4], XOR swizzle

    const int tid = threadIdx.x;
    const int g   = tid >> 2;          // group = chain row within block
    const int k   = tid & 3;           // tank role 0..3
    const int row = blockIdx.x * 16 + g;
    const int rowc = (row < B) ? row : (B - 1);
    const bool is0 = (k == 0);
    const bool is3 = (k == 3);
    const float zk = (k == 0) ? 0.0f : 1.0f;   // kills lane3->lane0 psum wrap

    const float v_r1h1 = p_r1h1[0], v_r1h2 = p_r1h2[0];
    const float v_h11 = p_h1h1[0], v_h12 = p_h1h2[0];
    const float v_ri2 = p_ri2[0], v_ro2 = p_ro2[0], v_h2 = p_h2[0];
    const float v_ri3 = p_ri3[0], v_ro3 = p_ro3[0], v_h3 = p_h3[0];
    const float v_ri4 = p_ri4[0], v_ro4 = p_ro4[0];
    const float scale = AreaP[0] * (1.0f / 3.6f);

    // Per-lane tank constants.
    float rA = v_ro4, kA = 0.0f, rB = 0.0f, kB = 0.0f, riN = 0.0f;
    if (k == 0) { rA = v_r1h1; kA = -v_r1h1 * v_h11; rB = v_r1h2; kB = -v_r1h2 * v_h12; riN = v_ri2; }
    else if (k == 1) { rA = v_ro2; kA = -v_ro2 * v_h2; riN = v_ri3; }
    else if (k == 2) { rA = v_ro3; kA = -v_ro3 * v_h3; riN = v_ri4; }

    float w = (k == 0) ? S0[0] : (k == 1) ? S0[1] : (k == 2) ? S0[2] : S0[3];

    int len = lengths[rowc];
    if (len > T) len = T;
    if (len < 0) len = 0;

    // Block-systolic state: this lane's 4 outflows / 4 running sums for the
    // block it just processed (rotated to the next lane at the next hop).
    float fl0 = 0.0f, fl1 = 0.0f, fl2 = 0.0f, fl3 = 0.0f;
    float ps0 = 0.0f, ps1 = 0.0f, ps2 = 0.0f, ps3 = 0.0f;
    const int ntiles = T / 64;         // 64 for T=4096 (even)

// One hop = 4 timesteps of one block. All DPPs are UNCONDITIONAL statements
// (convergent); lane-0 select afterwards on plain floats. Rotated values are
// consumed >=3 steps after the rotate: off the critical path. FREEZE (tile 0
// only) holds w until this lane's first real hop (hidx >= k).
#define HOP4(CX, CY, CZ, CW, FREEZE, hidx) do {                   \
        float r0_ = quad_rot1(fl0);                               \
        float r1_ = quad_rot1(fl1);                               \
        float r2_ = quad_rot1(fl2);                               \
        float r3_ = quad_rot1(fl3);                               \
        float q0_ = quad_rot1(ps0);                               \
        float q1_ = quad_rot1(ps1);                               \
        float q2_ = quad_rot1(ps2);                               \
        float q3_ = quad_rot1(ps3);                               \
        float i0_ = is0 ? (CX) : r0_;                             \
        float i1_ = is0 ? (CY) : r1_;                             \
        float i2_ = is0 ? (CZ) : r2_;                             \
        float i3_ = is0 ? (CW) : r3_;                             \
        float t_, a1_, a2_, e_, Y_, wn_;                          \
        /* step 0 */                                              \
        t_  = w + i0_;                                            \
        a1_ = fmaxf(fmaf(rA, t_, kA), 0.0f);                      \
        a2_ = fmaxf(fmaf(rB, t_, kB), 0.0f);                      \
        e_  = fmaxf(t_, 0.0f);                                    \
        fl0 = riN * e_;                                           \
        Y_  = a1_ + a2_;                                          \
        wn_ = (t_ - fl0) - Y_;                                    \
        w = (FREEZE) ? (((hidx) >= k) ? wn_ : w) : wn_;           \
        ps0 = fmaf(q0_, zk, Y_);                                  \
        /* step 1 */                                              \
        t_  = w + i1_;                                            \
        a1_ = fmaxf(fmaf(rA, t_, kA), 0.0f);                      \
        a2_ = fmaxf(fmaf(rB, t_, kB), 0.0f);                      \
        e_  = fmaxf(t_, 0.0f);                                    \
        fl1 = riN * e_;                                           \
        Y_  = a1_ + a2_;                                          \
        wn_ = (t_ - fl1) - Y_;                                    \
        w = (FREEZE) ? (((hidx) >= k) ? wn_ : w) : wn_;           \
        ps1 = fmaf(q1_, zk, Y_);                                  \
        /* step 2 */                                              \
        t_  = w + i2_;                                            \
        a1_ = fmaxf(fmaf(rA, t_, kA), 0.0f);                      \
        a2_ = fmaxf(fmaf(rB, t_, kB), 0.0f);                      \
        e_  = fmaxf(t_, 0.0f);                                    \
        fl2 = riN * e_;                                           \
        Y_  = a1_ + a2_;                                          \
        wn_ = (t_ - fl2) - Y_;                                    \
        w = (FREEZE) ? (((hidx) >= k) ? wn_ : w) : wn_;           \
        ps2 = fmaf(q2_, zk, Y_);                                  \
        /* step 3 */                                              \
        t_  = w + i3_;                                            \
        a1_ = fmaxf(fmaf(rA, t_, kA), 0.0f);                      \
        a2_ = fmaxf(fmaf(rB, t_, kB), 0.0f);                      \
        e_  = fmaxf(t_, 0.0f);                                    \
        fl3 = riN * e_;                                           \
        Y_  = a1_ + a2_;                                          \
        wn_ = (t_ - fl3) - Y_;                                    \
        w = (FREEZE) ? (((hidx) >= k) ? wn_ : w) : wn_;           \
        ps3 = fmaf(q3_, zk, Y_);                                  \
    } while (0)

// Global -> reg tile stage (coalesced 16B/lane segments; same as r3-r6).
#define STAGE_LOAD(stN, mt) do {                                          \
        const float* src_ = P + (size_t)rowc * T + (mt) * 64;             \
        _Pragma("unroll")                                                 \
        for (int r = 0; r < 4; ++r)                                       \
            stN[r] = *reinterpret_cast<const float4*>(src_ + (4 * r + k) * 4); \
    } while (0)

// Coop-store out-tile mt with scale + length masking.
#define OUT_STORE(mt) do {                                                \
        const float4* ob_ = outbuf + ((mt) % 3) * 256;                    \
        const int col0_ = (mt) * 64;                                      \
        _Pragma("unroll")                                                 \
        for (int r = 0; r < 4; ++r) {                                     \
            float4 v_ = ob_[g * 16 + ((4 * r + k) ^ g)];                  \
            const int cb_ = col0_ + (4 * r + k) * 4;                      \
            float4 s_;                                                    \
            s_.x = (cb_ + 0 < len) ? v_.x * scale : 0.0f;                 \
            s_.y = (cb_ + 1 < len) ? v_.y * scale : 0.0f;                 \
            s_.z = (cb_ + 2 < len) ? v_.z * scale : 0.0f;                 \
            s_.w = (cb_ + 3 < len) ? v_.w * scale : 0.0f;                 \
            if (row < B)                                                  \
                *reinterpret_cast<float4*>(Out + (size_t)row * T + cb_) = s_; \
        }                                                                 \
    } while (0)

// 16 hops over one reg-staged tile. Hop j's p block (timesteps 4j..4j+3) =
// quad broadcast from lane j&3 of stN[j>>2]. FULL unroll keeps the st index
// and dpp ctrl compile-time (rule: runtime-indexed reg arrays -> scratch).
// Lane3 completes one output block per hop -> outbuf.
#define TILE_BODY(FREEZE, h0, stN) do {                                   \
        _Pragma("unroll")                                                 \
        for (int j4 = 0; j4 < 16; ++j4) {                                 \
            const float4 pv_ = stN[j4 >> 2];                              \
            float px_ = quad_bcast(pv_.x, j4);                            \
            float py_ = quad_bcast(pv_.y, j4);                            \
            float pz_ = quad_bcast(pv_.z, j4);                            \
            float pw_ = quad_bcast(pv_.w, j4);                            \
            HOP4(px_, py_, pz_, pw_, FREEZE, j4);                         \
            const int b_ = (h0) + j4 - 3;                                 \
            if ((!(FREEZE) || b_ >= 0) && is3) {                          \
                float4* obp_ = outbuf + ((b_ >> 4) % 3) * 256;            \
                obp_[g * 16 + ((b_ & 15) ^ g)] =                          \
                    make_float4(ps0, ps1, ps2, ps3);                      \
            }                                                             \
        }                                                                 \
    } while (0)

    // ---- tile 0 (peeled: warm-up freeze active) ----
    float4 stA[4], stB[4];
    STAGE_LOAD(stA, 0);
    if (ntiles > 1) STAGE_LOAD(stB, 1);
    TILE_BODY(1, 0, stA);

    // ---- main tiles, pairwise (stB then stA), 1-tile prefetch distance ----
    #pragma clang loop unroll(disable)
    for (int m = 1; m + 1 < ntiles; m += 2) {
        STAGE_LOAD(stA, m + 1);
        if (m >= 3) OUT_STORE(m - 2);
        TILE_BODY(0, m * 16, stB);
        STAGE_LOAD(stB, m + 2);
        OUT_STORE(m - 1);
        TILE_BODY(0, (m + 1) * 16, stA);
    }

    // ---- peeled last tile (index ntiles-1, staged in stB) ----
    OUT_STORE(ntiles - 3);
    TILE_BODY(0, (ntiles - 1) * 16, stB);

    // Drain: 3 hops so lane3 completes blocks T/4-3 .. T/4-1. Lane0's p is
    // dead (its block indices >= T); rotated real data still propagates.
    {
        const int nb = T >> 2;
        #pragma unroll
        for (int d = 0; d < 3; ++d) {
            HOP4(0.0f, 0.0f, 0.0f, 0.0f, 0, 0);
            const int b_ = nb - 3 + d;
            if (is3) {
                float4* obp = outbuf + ((b_ >> 4) % 3) * 256;
                obp[g * 16 + ((b_ & 15) ^ g)] = make_float4(ps0, ps1, ps2, ps3);
            }
        }
    }
#undef HOP4
#undef TILE_BODY

    // Epilogue: store out-tiles ntiles-2, ntiles-1 (same-wave LDS order).
    OUT_STORE(ntiles - 2);
    OUT_STORE(ntiles - 1);
#undef OUT_STORE
#undef STAGE_LOAD
}

extern "C" void kernel_launch(void* const* d_in, const int* in_sizes, int n_in,
                              void* d_out, int out_size, void* d_ws, size_t ws_size,
                              hipStream_t stream) {
    const float* P        = (const float*)d_in[0];
    const int*   lengths  = (const int*)d_in[1];
    const float* S0       = (const float*)d_in[2];
    const float* Area     = (const float*)d_in[3];
    // d_in[4] = baseflow (unused by forward)
    const float* r1h1 = (const float*)d_in[5];
    const float* r1h2 = (const float*)d_in[6];
    const float* h1h1 = (const float*)d_in[7];
    const float* h1h2 = (const float*)d_in[8];
    const float* ri2  = (const float*)d_in[9];
    const float* ro2  = (const float*)d_in[10];
    const float* h2   = (const float*)d_in[11];
    const float* ri3  = (const float*)d_in[12];
    const float* ro3  = (const float*)d_in[13];
    const float* h3   = (const float*)d_in[14];
    const float* ri4  = (const float*)d_in[15];
    const float* ro4  = (const float*)d_in[16];
    float* out = (float*)d_out;

    const int B = in_sizes[1];
    const int T = in_sizes[0] / B;

    dim3 block(64);
    dim3 grid((B + 15) / 16);   // 16 chains per block (4 lanes/chain)
    hipLaunchKernelGGL(tank_kernel, grid, block, 0, stream,
                       P, lengths, S0, Area,
                       r1h1, r1h2, h1h1, h1h2,
                       ri2, ro2, h2, ri3, ro3, h3, ri4, ro4,
                       out, B, T);
}